// Round 11
// baseline (381.016 us; speedup 1.0000x reference)
//
#include <hip/hip_runtime.h>
#include <math.h>

#define NNODES 100000
#define NEDGES 1600000
#define NPOS   4096      // 32 seqs * 128 steps
#define NSEQ   32
#define TSTEPS 128

typedef float f32x4 __attribute__((ext_vector_type(4)));
typedef unsigned u32x4 __attribute__((ext_vector_type(4)));
typedef _Float16 h2v __attribute__((ext_vector_type(2)));

// ---- ws layout (bytes) ----
#define OFF_SLOT   0          // int[100000]  (dead after k_pregemm)
#define OFF_AGG    400128     // float[4096*128] (dead after k_pregemm; overlaid by wh16)
#define OFF_CNT    2497280    // float[4096]
#define OFF_WF     2513664    // float[1024*128]
#define OFF_BIASF  3037952    // float[1024]
#define OFF_PREG   3042048    // float[128][32s][8m][4q][32d]
#define OFF_HS     19819264   // float[129][32][256]
// fp16 weight images overlay the dead agg region (valid only after k_pregemm).
// Three-way split sized to the MEASURED constraints (R6-R10): VGPR budget is
// hard-capped at 128/wave @512thr; LDS 160KB; everything else streams from L2.
//   wR: u32[64][512]     register-resident   131072 B
//   wL: u32x4[18][512]   LDS-resident        147456 B
//   wS: u32x4[30][512]   L2-streamed/step    245760 B
#define OFF_WR  OFF_AGG
#define OFF_WL  (OFF_AGG + 131072)
#define OFF_WS  (OFF_AGG + 131072 + 147456)

// fp16 dot2 with f32 accumulate: D = w.h[0]*h.h[0] + w.h[1]*h.h[1] + acc.
static __device__ __forceinline__ float fdot2(unsigned w, unsigned h, float acc) {
#if __has_builtin(__builtin_amdgcn_fdot2)
  h2v wv, hv;
  __builtin_memcpy(&wv, &w, 4);
  __builtin_memcpy(&hv, &h, 4);
  return __builtin_amdgcn_fdot2(wv, hv, acc, false);
#else
  asm("v_dot2_f32_f16 %0, %1, %2, %0" : "+v"(acc) : "v"(w), "v"(h));
  return acc;
#endif
}

// one weight quad (4 packed pairs = 8 k) against one h quad
static __device__ __forceinline__ float dotq(u32x4 w, u32x4 h, float a) {
  a = fdot2(w[0], h[0], a);
  a = fdot2(w[1], h[1], a);
  a = fdot2(w[2], h[2], a);
  a = fdot2(w[3], h[3], a);
  return a;
}

// ---------------- init ----------------
__global__ void k_init(int* slotmap, float* agg, float* cnt, float* hs0) {
  int i = blockIdx.x * blockDim.x + threadIdx.x;
  int stride = gridDim.x * blockDim.x;
  for (int idx = i; idx < 4096 * 128; idx += stride) agg[idx] = 0.f;
  for (int idx = i; idx < NNODES; idx += stride) slotmap[idx] = -1;
  for (int idx = i; idx < 4096; idx += stride) cnt[idx] = 0.f;
  for (int idx = i; idx < 8192; idx += stride) hs0[idx] = 0.f;
}

// ---------------- mark needed nodes ----------------
__global__ void k_mark(const int* __restrict__ input_ids, int* __restrict__ slotmap) {
  int p = blockIdx.x * blockDim.x + threadIdx.x;
  if (p < NPOS) atomicCAS(&slotmap[input_ids[p]], -1, p);
}

// ---------------- edge pass: masked segment-sum ----------------
__global__ void k_edge(const int* __restrict__ src, const int* __restrict__ dst,
                       const float* __restrict__ ev, const float* __restrict__ emb,
                       const int* __restrict__ slotmap,
                       float* __restrict__ agg, float* __restrict__ cnt) {
  int e = blockIdx.x * 256 + threadIdx.x;
  int lane = threadIdx.x & 63;
  int d = dst[e];
  int slot = slotmap[d];
  int sn = 0; float vv = 0.f;
  if (slot >= 0) { sn = src[e]; vv = ev[e]; }
  unsigned long long m = __ballot(slot >= 0);
  while (m) {
    int j = __ffsll(m) - 1;
    m &= m - 1;
    int sl = __shfl(slot, j);
    int s2 = __shfl(sn, j);
    float v = __shfl(vv, j);
    float2 em = *(const float2*)&emb[(size_t)s2 * 128 + 2 * lane];
    atomicAdd(&agg[sl * 128 + 2 * lane],     em.x * v);
    atomicAdd(&agg[sl * 128 + 2 * lane + 1], em.y * v);
    if (lane == 0) atomicAdd(&cnt[sl], 1.f);
  }
}

// ---------------- divide by count ----------------
__global__ void k_div(float* __restrict__ agg, const float* __restrict__ cnt) {
  int i = blockIdx.x * blockDim.x + threadIdx.x;
  agg[i] /= fmaxf(cnt[i >> 7], 1.f);
}

// ---------------- fuse W_f = w_ih @ W1, bias_f ----------------
__global__ void k_fuse(const float* __restrict__ w_ih, const float* __restrict__ W1,
                       const float* __restrict__ b1, const float* __restrict__ b_ih,
                       const float* __restrict__ b_hh,
                       float* __restrict__ Wf, float* __restrict__ bf) {
  int row = blockIdx.x;
  int e = threadIdx.x;
  float acc = 0.f;
  for (int m2 = 0; m2 < 256; ++m2) acc += w_ih[row * 256 + m2] * W1[m2 * 128 + e];
  Wf[row * 128 + e] = acc;
  if (e == 0) {
    float bacc = b_ih[row] + b_hh[row];
    for (int m2 = 0; m2 < 256; ++m2) bacc += w_ih[row * 256 + m2] * b1[m2];
    bf[row] = bacc;
  }
}

// ---------------- pre-gates GEMM: preg[t][s][m][q][32d] ----------------
__global__ __launch_bounds__(256, 2) void k_pregemm(
    const float* __restrict__ hnode, const float* __restrict__ Wf,
    const float* __restrict__ bf, const int* __restrict__ slotmap,
    const int* __restrict__ input_ids, float* __restrict__ preg) {
  __shared__ float Ash[64][132];
  __shared__ float Bsh[64][132];
  __shared__ int slots[64];
  int tid = threadIdx.x;
  int bm = (blockIdx.x & 63) * 64;
  int bn = (blockIdx.x >> 6) * 64;
  if (tid < 64) slots[tid] = slotmap[input_ids[bm + tid]];
  __syncthreads();
#pragma unroll
  for (int i = 0; i < 8; ++i) {
    int idx = tid + 256 * i;
    int r = idx >> 5, c = idx & 31;
    *(float4*)&Ash[r][c * 4] = *(const float4*)&hnode[slots[r] * 128 + c * 4];
    *(float4*)&Bsh[r][c * 4] = *(const float4*)&Wf[(bn + r) * 128 + c * 4];
  }
  __syncthreads();
  int tx = tid & 15, ty = tid >> 4;
  float acc[4][4] = {};
  for (int k = 0; k < 128; k += 4) {
    float4 a[4], bb[4];
#pragma unroll
    for (int i = 0; i < 4; ++i) a[i] = *(const float4*)&Ash[tx + 16 * i][k];
#pragma unroll
    for (int j = 0; j < 4; ++j) bb[j] = *(const float4*)&Bsh[ty + 16 * j][k];
#pragma unroll
    for (int i = 0; i < 4; ++i)
#pragma unroll
      for (int j = 0; j < 4; ++j)
        acc[i][j] += a[i].x * bb[j].x + a[i].y * bb[j].y + a[i].z * bb[j].z + a[i].w * bb[j].w;
  }
#pragma unroll
  for (int j = 0; j < 4; ++j) {
    int row = bn + ty + 16 * j;
    float bias = bf[row];
    int q  = row >> 8;
    int mm = (row >> 5) & 7;
    int dl = row & 31;
#pragma unroll
    for (int i = 0; i < 4; ++i) {
      int p = bm + tx + 16 * i;
      int s = p >> 7, tt = p & 127;
      preg[(((size_t)(tt * 32 + s) * 8 + mm) * 4 + q) * 32 + dl] = acc[i][j] + bias;
    }
  }
}

// ---------------- w_hh f32 -> packed fp16 three-way images (RNE) ----------------
// k_lstm mapping: tid = kseg*128 + dd2 owns dims d0=2dd2, d1=2dd2+1, k-slice
// [64*kseg, 64*kseg+64). Row r = (d&1)*4 + q, phase b = pair p>>4, quad i, lane.
//   r<2                 -> REG  quad qr=(b*2+r)*4+i       (16 quads, 64 w)
//   b0 r3,r4 / b1 r2,r3 / b1 r4 i<2 -> LDS quads lc 0..17 (18 quads, 72 w)
//   rest                -> STREAM quads c 0..29 in CONSUMPTION order
__global__ void k_wcvt(const float* __restrict__ w_hh, unsigned* __restrict__ wR,
                       unsigned* __restrict__ wL, unsigned* __restrict__ wS) {
  int idx = blockIdx.x * 256 + threadIdx.x;   // 0..131071
  int row = idx >> 7;          // q*256 + dout
  int j   = idx & 127;         // pair index (k = 2j, 2j+1)
  float x0 = w_hh[(size_t)row * 256 + 2 * j];
  float x1 = w_hh[(size_t)row * 256 + 2 * j + 1];
  union { _Float16 f[2]; unsigned u; } pk;
  pk.f[0] = (_Float16)x0;
  pk.f[1] = (_Float16)x1;
  int q = row >> 8, dout = row & 255;
  int dim2 = dout & 1, dd2 = dout >> 1;
  int r = dim2 * 4 + q;
  int kseg = j >> 5, p = j & 31;
  int b = p >> 4, i = (p >> 2) & 3, lane = p & 3;
  int tid = kseg * 128 + dd2;
  if (r < 2) {
    int qr = (b * 2 + r) * 4 + i;
    wR[(qr * 4 + lane) * 512 + tid] = pk.u;
  } else if (b == 0 && (r == 3 || r == 4)) {
    wL[(((r - 3) * 4 + i) * 512 + tid) * 4 + lane] = pk.u;
  } else if (b == 1 && r == 2) {
    wL[((8 + i) * 512 + tid) * 4 + lane] = pk.u;
  } else if (b == 1 && r == 3) {
    wL[((12 + i) * 512 + tid) * 4 + lane] = pk.u;
  } else if (b == 1 && r == 4 && i < 2) {
    wL[((16 + i) * 512 + tid) * 4 + lane] = pk.u;
  } else if (b == 0 && r == 2) {
    wS[(i * 512 + tid) * 4 + lane] = pk.u;
  } else if (b == 0) {            // r>=5
    wS[((4 + (r - 5) * 4 + i) * 512 + tid) * 4 + lane] = pk.u;
  } else if (r == 4) {            // b==1, i>=2
    wS[((16 + (i - 2)) * 512 + tid) * 4 + lane] = pk.u;
  } else {                        // b==1, r>=5
    wS[((18 + (r - 5) * 4 + i) * 512 + tid) * 4 + lane] = pk.u;
  }
}

// ---------------- LSTM: one sequence per CU; reg/LDS/L2-stream weight split ----
// R6-R10 lesson: dur was ~206us regardless of spill volume => the cost is BYTES
// MOVED per step (DS ~85 B/cyc + VMEM ~100 B/cyc), and the VGPR budget is hard-
// capped (128 @512thr). So demand EXACTLY what fits: 64 reg words (16 u32x4,
// total demand ~126 <= 128 -> true residency, zero per-step cost), 72 LDS words
// (147 KB), 120 streamed words (246 KB/step from L2 -- image shared by all 4
// CUs of an XCD). Finer kseg split (4 x 64k, 2 dims/thread) halves h-broadcast
// DS reads. Per step: DS ~2400 cyc || VMEM ~2500 || VALU ~1200, + tail.
__global__ __launch_bounds__(512) void k_lstm(
    const unsigned* __restrict__ wR, const unsigned* __restrict__ wL,
    const unsigned* __restrict__ wS, const float* __restrict__ preg,
    float* __restrict__ hs) {
  __shared__ __align__(16) unsigned whL[18 * 512 * 4];  // 147456 B
  __shared__ __align__(16) unsigned h16[128];           // 256 fp16 h (512 B)
  __shared__ __align__(16) float    accb[3 * 128 * 8];  // 12288 B: kseg1..3 partials
  const int tid = threadIdx.x;
  const int s = blockIdx.x;
  const int kseg = tid >> 7;       // 0..3 : k-slice [64*kseg, 64*kseg+64)
  const int dd2 = tid & 127;       // dim pair: d0=2dd2, d1=2dd2+1
  const bool owner = (kseg == 0);

  // ---- prologue: 64 words -> VGPRs, 18 quads -> LDS (coalesced) ----
  u32x4 rq[16];
#pragma unroll
  for (int qr = 0; qr < 16; ++qr)
#pragma unroll
    for (int l = 0; l < 4; ++l)
      rq[qr][l] = wR[(qr * 4 + l) * 512 + tid];
  {
    const u32x4* src = (const u32x4*)wL;
    u32x4* dst = (u32x4*)whL;
#pragma unroll
    for (int lc = 0; lc < 18; ++lc)
      dst[lc * 512 + tid] = src[lc * 512 + tid];
  }
  if (tid < 128) h16[tid] = 0u;    // h(0) = 0 (fp16 pair)
  float c0s = 0.f, c1s = 0.f;      // cell states for d0, d1 (owners)
  __syncthreads();

  const u32x4* hqp = (const u32x4*)h16 + kseg * 8;  // 8 h-quads for this kseg
  const u32x4* lq = (const u32x4*)whL;              // lc*512 + tid
  const u32x4* sq = (const u32x4*)wS;               // c*512 + tid

  for (int t = 0; t < TSTEPS; ++t) {
    // owner pre-gates: d0,d1 are adjacent in preg's dl dimension -> float2
    float2 pg0, pg1, pg2, pg3;
    if (owner) {
      const float* pb = preg + (((size_t)(t * 32 + s) * 8 + (dd2 >> 4)) * 4) * 32
                        + ((2 * dd2) & 31);
      pg0 = *(const float2*)&pb[0];
      pg1 = *(const float2*)&pb[32];
      pg2 = *(const float2*)&pb[64];
      pg3 = *(const float2*)&pb[96];
    }
    float a0 = 0.f, a1 = 0.f, a2 = 0.f, a3 = 0.f;
    float a4 = 0.f, a5 = 0.f, a6 = 0.f, a7 = 0.f;
    // ================= phase b=0 (pairs 0..15, h quads 0..3) =================
    u32x4 A0 = sq[0 * 512 + tid], A1 = sq[1 * 512 + tid];
    u32x4 A2 = sq[2 * 512 + tid], A3 = sq[3 * 512 + tid];
    u32x4 B0 = sq[4 * 512 + tid], B1 = sq[5 * 512 + tid];
    u32x4 B2 = sq[6 * 512 + tid], B3 = sq[7 * 512 + tid];
    u32x4 h0 = hqp[0], h1 = hqp[1], h2 = hqp[2], h3 = hqp[3];
    a0 = dotq(rq[3], h3, dotq(rq[2], h2, dotq(rq[1], h1, dotq(rq[0], h0, a0))));
    a1 = dotq(rq[7], h3, dotq(rq[6], h2, dotq(rq[5], h1, dotq(rq[4], h0, a1))));
    a2 = dotq(A3, h3, dotq(A2, h2, dotq(A1, h1, dotq(A0, h0, a2))));      // r2b0
    u32x4 C0 = sq[8 * 512 + tid],  C1 = sq[9 * 512 + tid];
    u32x4 C2 = sq[10 * 512 + tid], C3 = sq[11 * 512 + tid];
    a3 = dotq(lq[3*512+tid], h3, dotq(lq[2*512+tid], h2,
         dotq(lq[1*512+tid], h1, dotq(lq[0*512+tid], h0, a3))));          // r3b0
    a4 = dotq(lq[7*512+tid], h3, dotq(lq[6*512+tid], h2,
         dotq(lq[5*512+tid], h1, dotq(lq[4*512+tid], h0, a4))));          // r4b0
    a5 = dotq(B3, h3, dotq(B2, h2, dotq(B1, h1, dotq(B0, h0, a5))));      // r5b0
    u32x4 D0 = sq[12 * 512 + tid], D1 = sq[13 * 512 + tid];
    u32x4 D2 = sq[14 * 512 + tid], D3 = sq[15 * 512 + tid];
    a6 = dotq(C3, h3, dotq(C2, h2, dotq(C1, h1, dotq(C0, h0, a6))));      // r6b0
    u32x4 E0 = sq[16 * 512 + tid], E1 = sq[17 * 512 + tid];
    u32x4 E2 = sq[18 * 512 + tid], E3 = sq[19 * 512 + tid];
    a7 = dotq(D3, h3, dotq(D2, h2, dotq(D1, h1, dotq(D0, h0, a7))));      // r7b0
    // ================= phase b=1 (pairs 16..31, h quads 4..7) ================
    h0 = hqp[4]; h1 = hqp[5]; h2 = hqp[6]; h3 = hqp[7];
    u32x4 F0 = sq[20 * 512 + tid], F1 = sq[21 * 512 + tid];
    u32x4 F2 = sq[22 * 512 + tid], F3 = sq[23 * 512 + tid];
    a0 = dotq(rq[11], h3, dotq(rq[10], h2, dotq(rq[9], h1, dotq(rq[8], h0, a0))));
    a1 = dotq(rq[15], h3, dotq(rq[14], h2, dotq(rq[13], h1, dotq(rq[12], h0, a1))));
    u32x4 G0 = sq[24 * 512 + tid], G1 = sq[25 * 512 + tid];
    u32x4 G2 = sq[26 * 512 + tid], G3 = sq[27 * 512 + tid];
    a2 = dotq(lq[11*512+tid], h3, dotq(lq[10*512+tid], h2,
         dotq(lq[9*512+tid], h1, dotq(lq[8*512+tid], h0, a2))));          // r2b1
    u32x4 H0 = sq[28 * 512 + tid], H1 = sq[29 * 512 + tid];
    a3 = dotq(lq[15*512+tid], h3, dotq(lq[14*512+tid], h2,
         dotq(lq[13*512+tid], h1, dotq(lq[12*512+tid], h0, a3))));        // r3b1
    a4 = dotq(E1, h3, dotq(E0, h2,
         dotq(lq[17*512+tid], h1, dotq(lq[16*512+tid], h0, a4))));        // r4b1
    a5 = dotq(F1, h3, dotq(F0, h2, dotq(E3, h1, dotq(E2, h0, a5))));      // r5b1
    a6 = dotq(G1, h3, dotq(G0, h2, dotq(F3, h1, dotq(F2, h0, a6))));      // r6b1
    a7 = dotq(H1, h3, dotq(H0, h2, dotq(G3, h1, dotq(G2, h0, a7))));      // r7b1
    // ---- publish partials (ksegs 1..3) ----
    if (!owner) {
      f32x4 pA; pA.x = a0; pA.y = a1; pA.z = a2; pA.w = a3;
      f32x4 pB; pB.x = a4; pB.y = a5; pB.z = a6; pB.w = a7;
      *(f32x4*)&accb[((kseg - 1) * 128 + dd2) * 8]     = pA;
      *(f32x4*)&accb[((kseg - 1) * 128 + dd2) * 8 + 4] = pB;
    }
    __syncthreads();                 // partials visible; h16 reads done
    if (owner) {
#pragma unroll
      for (int ks = 0; ks < 3; ++ks) {
        f32x4 pA = *(const f32x4*)&accb[(ks * 128 + dd2) * 8];
        f32x4 pB = *(const f32x4*)&accb[(ks * 128 + dd2) * 8 + 4];
        a0 += pA.x; a1 += pA.y; a2 += pA.z; a3 += pA.w;
        a4 += pB.x; a5 += pB.y; a6 += pB.z; a7 += pB.w;
      }
      float gi0 = a0 + pg0.x, gf0 = a1 + pg1.x, gg0 = a2 + pg2.x, go0 = a3 + pg3.x;
      float gi1 = a4 + pg0.y, gf1 = a5 + pg1.y, gg1 = a6 + pg2.y, go1 = a7 + pg3.y;
      float si0 = 1.f / (1.f + expf(-gi0));
      float sf0 = 1.f / (1.f + expf(-gf0));
      float so0 = 1.f / (1.f + expf(-go0));
      float cc0 = sf0 * c0s + si0 * tanhf(gg0);
      float hh0 = so0 * tanhf(cc0);
      c0s = cc0;
      float si1 = 1.f / (1.f + expf(-gi1));
      float sf1 = 1.f / (1.f + expf(-gf1));
      float so1 = 1.f / (1.f + expf(-go1));
      float cc1 = sf1 * c1s + si1 * tanhf(gg1);
      float hh1 = so1 * tanhf(cc1);
      c1s = cc1;
      union { _Float16 f[2]; unsigned u; } hp;
      hp.f[0] = (_Float16)hh0;
      hp.f[1] = (_Float16)hh1;
      h16[dd2] = hp.u;                                         // next-step h
      float2 hv; hv.x = hh0; hv.y = hh1;
      *(float2*)&hs[(size_t)(t + 1) * 8192 + s * 256 + 2 * dd2] = hv;  // history
    }
    __syncthreads();                 // new h16 + accb reuse protected
  }
}

// ---------------- final: scores, softmax, BCE, argmax ----------------
__global__ void k_final(const float* __restrict__ hs, const int* __restrict__ mask,
                        const float* __restrict__ labels, const float* __restrict__ W2,
                        const float* __restrict__ b2, float* __restrict__ out) {
  __shared__ float scores[32];
  __shared__ float errpart[8];
  int tid = threadIdx.x;
  if (tid < 32) {
    int len = 0;
    for (int t = 0; t < 128; ++t) len += mask[tid * 128 + t];
    if (len < 1) len = 1;
    const float* hl = hs + (size_t)len * 8192 + tid * 256;
    float acc = b2[0];
    for (int k = 0; k < 256; ++k) acc += hl[k] * W2[k];
    scores[tid] = acc;
  }
  __syncthreads();
  if (tid < 8) {
    float sc[4];
#pragma unroll
    for (int i = 0; i < 4; ++i) sc[i] = scores[tid * 4 + i];
    float mx = fmaxf(fmaxf(sc[0], sc[1]), fmaxf(sc[2], sc[3]));
    float ex[4], ssum = 0.f;
#pragma unroll
    for (int i = 0; i < 4; ++i) { ex[i] = expf(sc[i] - mx); ssum += ex[i]; }
    float esum = 0.f; int am = 0; float best = -1e30f;
#pragma unroll
    for (int i = 0; i < 4; ++i) {
      float p = ex[i] / ssum;
      float li = labels[tid * 4 + i];
      esum += fmaxf(p, 0.f) - p * li + log1pf(expf(-fabsf(p)));
      if (p > best) { best = p; am = i; }
    }
    errpart[tid] = esum;
    out[1 + tid] = (float)am;
  }
  __syncthreads();
  if (tid == 0) {
    float e = 0.f;
    for (int i = 0; i < 8; ++i) e += errpart[i];
    out[0] = e / 32.f;
  }
}

extern "C" void kernel_launch(void* const* d_in, const int* in_sizes, int n_in,
                              void* d_out, int out_size, void* d_ws, size_t ws_size,
                              hipStream_t stream) {
  const int*   input_ids  = (const int*)d_in[0];
  const int*   input_mask = (const int*)d_in[1];
  const float* labels     = (const float*)d_in[2];
  const int*   src        = (const int*)d_in[3];
  const int*   dst        = (const int*)d_in[4];
  const float* ev         = (const float*)d_in[5];
  const float* node_emb   = (const float*)d_in[6];
  const float* W1         = (const float*)d_in[7];
  const float* b1         = (const float*)d_in[8];
  const float* w_ih       = (const float*)d_in[9];
  const float* w_hh       = (const float*)d_in[10];
  const float* b_ih       = (const float*)d_in[11];
  const float* b_hh       = (const float*)d_in[12];
  const float* W2         = (const float*)d_in[13];
  const float* b2         = (const float*)d_in[14];
  float* out = (float*)d_out;
  char* ws = (char*)d_ws;
  int*      slotmap = (int*)(ws + OFF_SLOT);
  float*    agg     = (float*)(ws + OFF_AGG);
  float*    cnt     = (float*)(ws + OFF_CNT);
  float*    Wf      = (float*)(ws + OFF_WF);
  float*    biasf   = (float*)(ws + OFF_BIASF);
  float*    preg    = (float*)(ws + OFF_PREG);
  float*    hs      = (float*)(ws + OFF_HS);
  unsigned* wRimg   = (unsigned*)(ws + OFF_WR);
  unsigned* wLimg   = (unsigned*)(ws + OFF_WL);
  unsigned* wSimg   = (unsigned*)(ws + OFF_WS);

  hipLaunchKernelGGL(k_init,    dim3(2048), dim3(256), 0, stream, slotmap, agg, cnt, hs);
  hipLaunchKernelGGL(k_mark,    dim3(16),   dim3(256), 0, stream, input_ids, slotmap);
  hipLaunchKernelGGL(k_edge,    dim3(6250), dim3(256), 0, stream, src, dst, ev, node_emb, slotmap, agg, cnt);
  hipLaunchKernelGGL(k_div,     dim3(2048), dim3(256), 0, stream, agg, cnt);
  hipLaunchKernelGGL(k_fuse,    dim3(1024), dim3(128), 0, stream, w_ih, W1, b1, b_ih, b_hh, Wf, biasf);
  hipLaunchKernelGGL(k_pregemm, dim3(1024), dim3(256), 0, stream, agg, Wf, biasf, slotmap, input_ids, preg);
  hipLaunchKernelGGL(k_wcvt,    dim3(512),  dim3(256), 0, stream, w_hh, wRimg, wLimg, wSimg);
  hipLaunchKernelGGL(k_lstm,    dim3(NSEQ), dim3(512), 0, stream, wRimg, wLimg, wSimg, preg, hs);
  hipLaunchKernelGGL(k_final,   dim3(1),    dim3(64),  0, stream, hs, input_mask, labels, W2, b2, out);
}